// Round 6
// baseline (271.924 us; speedup 1.0000x reference)
//
#include <hip/hip_runtime.h>

// Soft-DTW gradient, batch=64, 256x256, gamma=0.01 — forward/backward-DP form.
// R20: linear-domain DP in F64 + asm-pinned theta prefetch.
// R18/R19 post-mortem: the f32 block-floating window (~200 bits below anchor)
// cannot span the within-tile V' spread (up to 8*144 ≈ 1160 bits) -> the
// final corner cell flushes -> Ftot=+inf -> inf-inf = NaN (deterministic).
// Also the "flushed => E≈0" argument needs a window > K2*(merge dist ~8)
// ≈ 1150 bits — f32 can never be safe. F64's ~2046-bit window covers it:
// flushed cells are >=1700 bits below a cell <=8 steps away =>
// E <= 2^(144+1152-1700) = 2^-404 ~ 0, provably negligible.
// DP: W(i,j) = 2^(-K2*th) * (W_l + W_d + W_u), u = W*2^S per-lane f64 frame,
// ONE anchor per body (no per-column rescales -> R18/R19 hazard nest gone).
// Chain/cell = f64 add + f64 mul (~12cy vs ~250cy transcendental softmin).
// p = 2^(-K2*th) built off-chain: exp2f(frac) -> f64 ldexp(., int) — exact.
// Store path off-chain: V' = (S - e) - log2f(mant); denormal/zero -> +inf.
// Theta prefetch: inline-asm global_load_dwordx4 (cannot be sunk by
// regalloc — R16/R17 showed the compiler de-pipelines C loads, VGPR stuck
// at 48) + counted s_waitcnt vmcnt(8) + sched_barrier(0) before consumption
// = true 2-body-deep pipeline (loads lead consumption by ~2 body times).
// Structure: one wave/block, 64 lanes, R=4 rows/lane, skew m=g+L, shuffle
// exchange (4 f64 + frame int), 129 bodies. 128 blocks: 0..63 = F DP,
// 64..127 = B DP (index-reversed, stored mirrored). Device-scope flag
// barrier, fused epilogue E = exp2(K2*th + F'tot - F' - B') + batch mean.
// ws: F planes [64][65536] f32, B planes [64][65536] f32, counter u32.

#define MM 256
#define NN 256
#define R 4              // rows per lane
#define NB 64            // batch elements
#define NBLK 128         // DP blocks: 64 forward + 64 backward
#define K2   144.269504089f     // 1/(gamma*ln2) = (1/gamma)*log2(e)
#define TB64 1700        // target biased exponent (f64) for frame anchor

typedef float f32x4 __attribute__((ext_vector_type(4)));

__device__ __forceinline__ int iclamp(int x, int lo, int hi) {
    return x < lo ? lo : (x > hi ? hi : x);
}
__device__ __forceinline__ int imax(int a, int b) { return a > b ? a : b; }
// f64 biased exponent; 0 for zero/denormal (treated as dead).
__device__ __forceinline__ int bexp64(double x) {
    return (int)(((unsigned long long)__double_as_longlong(x) >> 52) & 2047u);
}
// reconciled exponent of a foreign-frame value (dead contributes 0).
__device__ __forceinline__ int rexp64(double x, int d) {
    const int e = bexp64(x);
    return e == 0 ? 0 : e + d;
}

// One soft-DTW DP over the virtual matrix, f64 linear domain.
// REV=false: virtual == physical (computes F').
// REV=true : virtual (i,j) = physical (255-i,255-j) (computes B', mirrored).
template<bool REV>
__device__ __forceinline__ void run_dp(const float* __restrict__ th,
                                       float* __restrict__ Vp)
{
    const int L = threadIdx.x;                      // 0..63

    double up[R];                // own rows' right-edge u (frame S)
    double rcv[4];               // neighbor bottom row (frame recS)
    double bot[4];               // own bottom row to send (frame S)
    double prevW = 0.0;          // top-left diag value (frame prevWS)
    #pragma unroll
    for (int r = 0; r < R; ++r) up[r] = 0.0;
    #pragma unroll
    for (int j = 0; j < 4; ++j) { rcv[j] = 0.0; bot[j] = 0.0; }
    int S = 0, recS = 0, prevWS = 0;
    f32x4 thB[3][R];
    #pragma unroll
    for (int p = 0; p < 3; ++p)
        #pragma unroll
        for (int r = 0; r < R; ++r) thB[p][r] = (f32x4)0.0f;

    auto body = [&](const int LD, const int CU, const int m) {
        const int g = m - L;
        const int gl = iclamp(g + 2, 0, 63);        // prefetch distance 2
        #pragma unroll
        for (int r = 0; r < R; ++r) {
            const int vr = 4 * L + r;
            const float* addr = REV ? (th + (255 - vr) * NN + (252 - 4 * gl))
                                    : (th + vr * NN + 4 * gl);
            asm volatile("global_load_dwordx4 %0, %1, off"
                         : "=v"(thB[LD][r]) : "v"(addr));
        }
        if ((unsigned)g <= 63u) {
            // loads issued 2 bodies ago are older than the newest 8 loads
            asm volatile("s_waitcnt vmcnt(8)" ::: "memory");
            __builtin_amdgcn_sched_barrier(0);

            // ---- per-body anchor: reconcile frames, center max at TB64 ----
            const int drec = S - recS, dpw = S - prevWS;
            int em = bexp64(up[0]);
            em = imax(em, bexp64(up[1])); em = imax(em, bexp64(up[2]));
            em = imax(em, bexp64(up[3]));
            em = imax(em, rexp64(rcv[0], drec)); em = imax(em, rexp64(rcv[1], drec));
            em = imax(em, rexp64(rcv[2], drec)); em = imax(em, rexp64(rcv[3], drec));
            em = imax(em, rexp64(prevW, dpw));
            if (g == 0 && L == 0) em = imax(em, 1023 + S);   // corner seed
            const int k0 = em - TB64;
            S -= k0;
            #pragma unroll
            for (int j = 0; j < 4; ++j) rcv[j] = ldexp(rcv[j], drec - k0);
            prevW = ldexp(prevW, dpw - k0);
            #pragma unroll
            for (int r = 0; r < R; ++r) up[r] = ldexp(up[r], -k0);
            const double ud0 = (g == 0) ? ((L == 0) ? ldexp(1.0, S) : 0.0)
                                        : prevW;

            // ---- 4 columns x 4 rows, f64 linear cells (no col rescale) ----
            float vbuf[R][4];
            #pragma unroll
            for (int cc = 0; cc < 4; ++cc) {
                // off-chain: p = 2^(-K2*th) as exact f64
                double pdc[R];
                #pragma unroll
                for (int r = 0; r < R; ++r) {
                    const float thv = thB[CU][r][REV ? 3 - cc : cc];
                    const float f  = -K2 * thv;
                    const float fi = rintf(f);
                    pdc[r] = ldexp((double)exp2f(f - fi), (int)fi);
                }
                // off-chain: pre[r] = diag + left (both previous-col values)
                double pre[R];
                pre[0] = ((cc == 0) ? ud0 : rcv[cc - 1]) + up[0];
                #pragma unroll
                for (int r = 1; r < R; ++r) pre[r] = up[r - 1] + up[r];
                double vu = rcv[cc];
                #pragma unroll
                for (int r = 0; r < R; ++r) {
                    const double un = pdc[r] * (pre[r] + vu);   // the chain
                    // store path (off-chain): V' = (S - e) - log2(mant)
                    const long long ub = __double_as_longlong(un);
                    const int ef = (int)(((unsigned long long)ub >> 52) & 2047u);
                    const double mant = __longlong_as_double(
                        (ub & 0x000FFFFFFFFFFFFFLL) | 0x3FF0000000000000LL);
                    vbuf[r][cc] = (ef == 0)
                        ? __builtin_inff()
                        : ((float)(S - (ef - 1023)) - log2f((float)mant));
                    if (r == R - 1) bot[cc] = un;
                    vu = un; up[r] = un;
                }
            }
            recS = S;            // rcv now lives in frame S
            #pragma unroll
            for (int r = 0; r < R; ++r) {
                const int vr = 4 * L + r;
                if (REV) {
                    f32x4 sv = {vbuf[r][3], vbuf[r][2], vbuf[r][1], vbuf[r][0]};
                    *(f32x4*)(Vp + (255 - vr) * NN + (252 - 4 * g)) = sv;
                } else {
                    f32x4 sv = {vbuf[r][0], vbuf[r][1], vbuf[r][2], vbuf[r][3]};
                    *(f32x4*)(Vp + vr * NN + 4 * g) = sv;
                }
            }
        }
        // ---- in-wave exchange: lane L receives lane L-1's bottom + frame ----
        const double nb0 = __shfl_up(bot[0], 1);
        const double nb1 = __shfl_up(bot[1], 1);
        const double nb2 = __shfl_up(bot[2], 1);
        const double nb3 = __shfl_up(bot[3], 1);
        const int   nbS = __shfl_up(S, 1);
        prevW = rcv[3]; prevWS = recS;              // old rcv.w -> next diag
        rcv[0] = nb0; rcv[1] = nb1; rcv[2] = nb2; rcv[3] = nb3; recS = nbS;
        if (L == 0) { rcv[0] = rcv[1] = rcv[2] = rcv[3] = 0.0; recS = S; }
    };
    for (int k = 0; k < 129; k += 3) {              // m = -2 .. 126
        body(0, 1, k - 2);
        body(1, 2, k - 1);
        body(2, 0, k);
    }
}

__global__ __launch_bounds__(64, 1) void dtw_fb(
    const float* __restrict__ D,
    float* __restrict__ out,          // [256][256]
    float* __restrict__ ws)
{
    const int blk = blockIdx.x;
    const bool rev = blk >= NB;
    const int b = rev ? blk - NB : blk;
    const float* __restrict__ th = D + (size_t)b * (MM * NN);
    float* __restrict__ Fp = ws + (size_t)b * (MM * NN);
    float* __restrict__ Bp = ws + (size_t)(NB + b) * (MM * NN);
    unsigned* ctr = (unsigned*)(ws + (size_t)2 * NB * (MM * NN));

    if (rev) run_dp<true >(th, Bp);
    else     run_dp<false>(th, Fp);

    // ---------------- device-scope barrier (128 blocks, 1 wave each) ----------------
    __threadfence();                   // release V-plane stores (L2 writeback)
    if (threadIdx.x == 0)
        __hip_atomic_fetch_add(ctr, 1u, __ATOMIC_ACQ_REL, __HIP_MEMORY_SCOPE_AGENT);
    unsigned cnt;
    do {
        cnt = __hip_atomic_load(ctr, __ATOMIC_ACQUIRE, __HIP_MEMORY_SCOPE_AGENT);
        if (cnt < NBLK) __builtin_amdgcn_s_sleep(2);
    } while (cnt < NBLK);
    __builtin_amdgcn_fence(__ATOMIC_ACQUIRE, "agent");   // invalidate caches

    // ---------------- fused epilogue + batch mean ----------------
    // E_b(i,j) = exp2( K2*theta + F'tot_b - F'_b(i,j) - B'_b(i,j) );
    // block blk owns output rows 2*blk, 2*blk+1; thread t: row 2*blk+(t>>5),
    // cols 4*(t&31) and 4*(t&31)+128.  (+inf planes -> -inf -> exp2 -> 0.)
    {
        const int t = threadIdx.x;
        const int row = 2 * blk + (t >> 5);
        const int cb  = 4 * (t & 31);
        const size_t off0 = (size_t)row * NN + cb;
        const size_t off1 = off0 + 128;
        float4 acc0 = make_float4(0.f, 0.f, 0.f, 0.f);
        float4 acc1 = make_float4(0.f, 0.f, 0.f, 0.f);
        for (int p = 0; p < NB; ++p) {
            const float* __restrict__ thp = D + (size_t)p * (MM * NN);
            const float* __restrict__ fp  = ws + (size_t)p * (MM * NN);
            const float* __restrict__ bp  = ws + (size_t)(NB + p) * (MM * NN);
            const float Ft = fp[MM * NN - 1];                 // F'tot = F'(M,N)
            const float4 t0 = *(const float4*)(thp + off0);
            const float4 f0 = *(const float4*)(fp + off0);
            const float4 b0 = *(const float4*)(bp + off0);
            acc0.x += exp2f(fmaf(t0.x, K2, (Ft - f0.x) - b0.x));
            acc0.y += exp2f(fmaf(t0.y, K2, (Ft - f0.y) - b0.y));
            acc0.z += exp2f(fmaf(t0.z, K2, (Ft - f0.z) - b0.z));
            acc0.w += exp2f(fmaf(t0.w, K2, (Ft - f0.w) - b0.w));
            const float4 t1 = *(const float4*)(thp + off1);
            const float4 f1 = *(const float4*)(fp + off1);
            const float4 b1 = *(const float4*)(bp + off1);
            acc1.x += exp2f(fmaf(t1.x, K2, (Ft - f1.x) - b1.x));
            acc1.y += exp2f(fmaf(t1.y, K2, (Ft - f1.y) - b1.y));
            acc1.z += exp2f(fmaf(t1.z, K2, (Ft - f1.z) - b1.z));
            acc1.w += exp2f(fmaf(t1.w, K2, (Ft - f1.w) - b1.w));
        }
        const float inv = 1.0f / (float)NB;
        *(float4*)(out + off0) =
            make_float4(acc0.x * inv, acc0.y * inv, acc0.z * inv, acc0.w * inv);
        *(float4*)(out + off1) =
            make_float4(acc1.x * inv, acc1.y * inv, acc1.z * inv, acc1.w * inv);
    }
}

extern "C" void kernel_launch(void* const* d_in, const int* in_sizes, int n_in,
                              void* d_out, int out_size, void* d_ws, size_t ws_size,
                              hipStream_t stream) {
    const float* D = (const float*)d_in[0];
    float* out = (float*)d_out;
    float* ws = (float*)d_ws;

    // zero the barrier counter (ws is re-poisoned 0xAA before every launch)
    hipMemsetAsync(ws + (size_t)2 * NB * (MM * NN), 0, sizeof(unsigned), stream);
    dtw_fb<<<dim3(NBLK), dim3(64), 0, stream>>>(D, out, ws);
}

// Round 7
// 268.567 us; speedup vs baseline: 1.0125x; 1.0125x over previous
//
#include <hip/hip_runtime.h>

// Soft-DTW gradient, batch=64, 256x256, gamma=0.01 — forward/backward-DP form.
// R21 = R20 (f64 linear-domain DP, asm-pinned prefetch) with the vmcnt wait
// corrected from 8 -> 16.
// R20 post-mortem: removing all on-chain transcendentals (f64 cell) AND
// pinning the prefetch changed nothing (215us, 4000cy/body, VALU issue only
// ~650cy/body). The stall is the wait itself: vmcnt counts STORES too, and
// retires in issue order. Steady-state queue at body k's wait:
//   [S_{k-3}(4), L_{k-2}(4), S_{k-2}(4), L_{k-1}(4), S_{k-1}(4), L_k(4)] = 24.
// vmcnt(8) drains 16 -> waits for S_{k-2} (the PREVIOUS body's 4 scattered
// 64-line store-acks, write-allocate to HBM-backed ws) + L_{k-1}. That gates
// every body on store completion ≈ the ~3300cy/body stall.
// vmcnt(16) drains exactly S_{k-3} + L_{k-2}: the loads consumed this body
// (2-body lead ≈ 8000cy >> 900cy HBM) and 3-body-old store-acks. Warm-up:
// bodies 0,1 issue loads but no stores (guard all-false), so the queue is
// 8 short; the bodies consuming L0 and L1 (3rd and 4th bodies) need waits
// 8 and 12 respectively -> first two loop iterations peeled with explicit
// wait counts. Everything else byte-identical to R20.
// Math/structure (from R20): W(i,j)=2^(-K2*th)*(Wl+Wd+Wu), u=W*2^S per-lane
// f64 frame, one anchor per body; V' = (S-e) - log2(mant) stored f32;
// one wave/block, 64 lanes, R=4 rows/lane, skew m=g+L, shuffle exchange;
// 128 blocks (0..63 F, 64..127 B reversed/mirrored); device-scope flag
// barrier; fused epilogue E = exp2(K2*th + F'tot - F' - B') + batch mean.
// ws: F planes [64][65536] f32, B planes [64][65536] f32, counter u32.

#define MM 256
#define NN 256
#define R 4              // rows per lane
#define NB 64            // batch elements
#define NBLK 128         // DP blocks: 64 forward + 64 backward
#define K2   144.269504089f     // 1/(gamma*ln2) = (1/gamma)*log2(e)
#define TB64 1700        // target biased exponent (f64) for frame anchor

typedef float f32x4 __attribute__((ext_vector_type(4)));

__device__ __forceinline__ int iclamp(int x, int lo, int hi) {
    return x < lo ? lo : (x > hi ? hi : x);
}
__device__ __forceinline__ int imax(int a, int b) { return a > b ? a : b; }
// f64 biased exponent; 0 for zero/denormal (treated as dead).
__device__ __forceinline__ int bexp64(double x) {
    return (int)(((unsigned long long)__double_as_longlong(x) >> 52) & 2047u);
}
// reconciled exponent of a foreign-frame value (dead contributes 0).
__device__ __forceinline__ int rexp64(double x, int d) {
    const int e = bexp64(x);
    return e == 0 ? 0 : e + d;
}

// One soft-DTW DP over the virtual matrix, f64 linear domain.
// REV=false: virtual == physical (computes F').
// REV=true : virtual (i,j) = physical (255-i,255-j) (computes B', mirrored).
template<bool REV>
__device__ __forceinline__ void run_dp(const float* __restrict__ th,
                                       float* __restrict__ Vp)
{
    const int L = threadIdx.x;                      // 0..63

    double up[R];                // own rows' right-edge u (frame S)
    double rcv[4];               // neighbor bottom row (frame recS)
    double bot[4];               // own bottom row to send (frame S)
    double prevW = 0.0;          // top-left diag value (frame prevWS)
    #pragma unroll
    for (int r = 0; r < R; ++r) up[r] = 0.0;
    #pragma unroll
    for (int j = 0; j < 4; ++j) { rcv[j] = 0.0; bot[j] = 0.0; }
    int S = 0, recS = 0, prevWS = 0;
    f32x4 thB[3][R];
    #pragma unroll
    for (int p = 0; p < 3; ++p)
        #pragma unroll
        for (int r = 0; r < R; ++r) thB[p][r] = (f32x4)0.0f;

    auto body = [&](const int LD, const int CU, const int m, const int WN) {
        const int g = m - L;
        const int gl = iclamp(g + 2, 0, 63);        // prefetch distance 2
        #pragma unroll
        for (int r = 0; r < R; ++r) {
            const int vr = 4 * L + r;
            const float* addr = REV ? (th + (255 - vr) * NN + (252 - 4 * gl))
                                    : (th + vr * NN + 4 * gl);
            asm volatile("global_load_dwordx4 %0, %1, off"
                         : "=v"(thB[LD][r]) : "v"(addr));
        }
        // Counted wait (outside the guard: executes every body, keeps the
        // in-order vmcnt arithmetic deterministic). WN is a call-site
        // literal -> constant-folds after inlining.
        if (WN == 8)       asm volatile("s_waitcnt vmcnt(8)"  ::: "memory");
        else if (WN == 12) asm volatile("s_waitcnt vmcnt(12)" ::: "memory");
        else               asm volatile("s_waitcnt vmcnt(16)" ::: "memory");
        __builtin_amdgcn_sched_barrier(0);

        if ((unsigned)g <= 63u) {
            // ---- per-body anchor: reconcile frames, center max at TB64 ----
            const int drec = S - recS, dpw = S - prevWS;
            int em = bexp64(up[0]);
            em = imax(em, bexp64(up[1])); em = imax(em, bexp64(up[2]));
            em = imax(em, bexp64(up[3]));
            em = imax(em, rexp64(rcv[0], drec)); em = imax(em, rexp64(rcv[1], drec));
            em = imax(em, rexp64(rcv[2], drec)); em = imax(em, rexp64(rcv[3], drec));
            em = imax(em, rexp64(prevW, dpw));
            if (g == 0 && L == 0) em = imax(em, 1023 + S);   // corner seed
            const int k0 = em - TB64;
            S -= k0;
            #pragma unroll
            for (int j = 0; j < 4; ++j) rcv[j] = ldexp(rcv[j], drec - k0);
            prevW = ldexp(prevW, dpw - k0);
            #pragma unroll
            for (int r = 0; r < R; ++r) up[r] = ldexp(up[r], -k0);
            const double ud0 = (g == 0) ? ((L == 0) ? ldexp(1.0, S) : 0.0)
                                        : prevW;

            // ---- 4 columns x 4 rows, f64 linear cells (no col rescale) ----
            float vbuf[R][4];
            #pragma unroll
            for (int cc = 0; cc < 4; ++cc) {
                // off-chain: p = 2^(-K2*th) as exact f64
                double pdc[R];
                #pragma unroll
                for (int r = 0; r < R; ++r) {
                    const float thv = thB[CU][r][REV ? 3 - cc : cc];
                    const float f  = -K2 * thv;
                    const float fi = rintf(f);
                    pdc[r] = ldexp((double)exp2f(f - fi), (int)fi);
                }
                // off-chain: pre[r] = diag + left (both previous-col values)
                double pre[R];
                pre[0] = ((cc == 0) ? ud0 : rcv[cc - 1]) + up[0];
                #pragma unroll
                for (int r = 1; r < R; ++r) pre[r] = up[r - 1] + up[r];
                double vu = rcv[cc];
                #pragma unroll
                for (int r = 0; r < R; ++r) {
                    const double un = pdc[r] * (pre[r] + vu);   // the chain
                    // store path (off-chain): V' = (S - e) - log2(mant)
                    const long long ub = __double_as_longlong(un);
                    const int ef = (int)(((unsigned long long)ub >> 52) & 2047u);
                    const double mant = __longlong_as_double(
                        (ub & 0x000FFFFFFFFFFFFFLL) | 0x3FF0000000000000LL);
                    vbuf[r][cc] = (ef == 0)
                        ? __builtin_inff()
                        : ((float)(S - (ef - 1023)) - log2f((float)mant));
                    if (r == R - 1) bot[cc] = un;
                    vu = un; up[r] = un;
                }
            }
            recS = S;            // rcv now lives in frame S
            #pragma unroll
            for (int r = 0; r < R; ++r) {
                const int vr = 4 * L + r;
                if (REV) {
                    f32x4 sv = {vbuf[r][3], vbuf[r][2], vbuf[r][1], vbuf[r][0]};
                    *(f32x4*)(Vp + (255 - vr) * NN + (252 - 4 * g)) = sv;
                } else {
                    f32x4 sv = {vbuf[r][0], vbuf[r][1], vbuf[r][2], vbuf[r][3]};
                    *(f32x4*)(Vp + vr * NN + 4 * g) = sv;
                }
            }
        }
        // ---- in-wave exchange: lane L receives lane L-1's bottom + frame ----
        const double nb0 = __shfl_up(bot[0], 1);
        const double nb1 = __shfl_up(bot[1], 1);
        const double nb2 = __shfl_up(bot[2], 1);
        const double nb3 = __shfl_up(bot[3], 1);
        const int   nbS = __shfl_up(S, 1);
        prevW = rcv[3]; prevWS = recS;              // old rcv.w -> next diag
        rcv[0] = nb0; rcv[1] = nb1; rcv[2] = nb2; rcv[3] = nb3; recS = nbS;
        if (L == 0) { rcv[0] = rcv[1] = rcv[2] = rcv[3] = 0.0; recS = S; }
    };
    // Warm-up peel: bodies 0,1 issue loads only (no stores), so the vmcnt
    // queue is 8 short of steady state. Body consuming L0 needs <=8, the
    // one consuming L1 needs <=12; from L2 on, 16 is exact.
    body(0, 1, -2, 16);
    body(1, 2, -1, 16);
    body(2, 0,  0,  8);
    body(0, 1,  1, 12);
    body(1, 2,  2, 16);
    body(2, 0,  3, 16);
    for (int k = 6; k < 129; k += 3) {              // m = 4 .. 126
        body(0, 1, k - 2, 16);
        body(1, 2, k - 1, 16);
        body(2, 0, k,     16);
    }
}

__global__ __launch_bounds__(64, 1) void dtw_fb(
    const float* __restrict__ D,
    float* __restrict__ out,          // [256][256]
    float* __restrict__ ws)
{
    const int blk = blockIdx.x;
    const bool rev = blk >= NB;
    const int b = rev ? blk - NB : blk;
    const float* __restrict__ th = D + (size_t)b * (MM * NN);
    float* __restrict__ Fp = ws + (size_t)b * (MM * NN);
    float* __restrict__ Bp = ws + (size_t)(NB + b) * (MM * NN);
    unsigned* ctr = (unsigned*)(ws + (size_t)2 * NB * (MM * NN));

    if (rev) run_dp<true >(th, Bp);
    else     run_dp<false>(th, Fp);

    // ---------------- device-scope barrier (128 blocks, 1 wave each) ----------------
    __threadfence();                   // release V-plane stores (L2 writeback)
    if (threadIdx.x == 0)
        __hip_atomic_fetch_add(ctr, 1u, __ATOMIC_ACQ_REL, __HIP_MEMORY_SCOPE_AGENT);
    unsigned cnt;
    do {
        cnt = __hip_atomic_load(ctr, __ATOMIC_ACQUIRE, __HIP_MEMORY_SCOPE_AGENT);
        if (cnt < NBLK) __builtin_amdgcn_s_sleep(2);
    } while (cnt < NBLK);
    __builtin_amdgcn_fence(__ATOMIC_ACQUIRE, "agent");   // invalidate caches

    // ---------------- fused epilogue + batch mean ----------------
    // E_b(i,j) = exp2( K2*theta + F'tot_b - F'_b(i,j) - B'_b(i,j) );
    // block blk owns output rows 2*blk, 2*blk+1; thread t: row 2*blk+(t>>5),
    // cols 4*(t&31) and 4*(t&31)+128.  (+inf planes -> -inf -> exp2 -> 0.)
    {
        const int t = threadIdx.x;
        const int row = 2 * blk + (t >> 5);
        const int cb  = 4 * (t & 31);
        const size_t off0 = (size_t)row * NN + cb;
        const size_t off1 = off0 + 128;
        float4 acc0 = make_float4(0.f, 0.f, 0.f, 0.f);
        float4 acc1 = make_float4(0.f, 0.f, 0.f, 0.f);
        for (int p = 0; p < NB; ++p) {
            const float* __restrict__ thp = D + (size_t)p * (MM * NN);
            const float* __restrict__ fp  = ws + (size_t)p * (MM * NN);
            const float* __restrict__ bp  = ws + (size_t)(NB + p) * (MM * NN);
            const float Ft = fp[MM * NN - 1];                 // F'tot = F'(M,N)
            const float4 t0 = *(const float4*)(thp + off0);
            const float4 f0 = *(const float4*)(fp + off0);
            const float4 b0 = *(const float4*)(bp + off0);
            acc0.x += exp2f(fmaf(t0.x, K2, (Ft - f0.x) - b0.x));
            acc0.y += exp2f(fmaf(t0.y, K2, (Ft - f0.y) - b0.y));
            acc0.z += exp2f(fmaf(t0.z, K2, (Ft - f0.z) - b0.z));
            acc0.w += exp2f(fmaf(t0.w, K2, (Ft - f0.w) - b0.w));
            const float4 t1 = *(const float4*)(thp + off1);
            const float4 f1 = *(const float4*)(fp + off1);
            const float4 b1 = *(const float4*)(bp + off1);
            acc1.x += exp2f(fmaf(t1.x, K2, (Ft - f1.x) - b1.x));
            acc1.y += exp2f(fmaf(t1.y, K2, (Ft - f1.y) - b1.y));
            acc1.z += exp2f(fmaf(t1.z, K2, (Ft - f1.z) - b1.z));
            acc1.w += exp2f(fmaf(t1.w, K2, (Ft - f1.w) - b1.w));
        }
        const float inv = 1.0f / (float)NB;
        *(float4*)(out + off0) =
            make_float4(acc0.x * inv, acc0.y * inv, acc0.z * inv, acc0.w * inv);
        *(float4*)(out + off1) =
            make_float4(acc1.x * inv, acc1.y * inv, acc1.z * inv, acc1.w * inv);
    }
}

extern "C" void kernel_launch(void* const* d_in, const int* in_sizes, int n_in,
                              void* d_out, int out_size, void* d_ws, size_t ws_size,
                              hipStream_t stream) {
    const float* D = (const float*)d_in[0];
    float* out = (float*)d_out;
    float* ws = (float*)d_ws;

    // zero the barrier counter (ws is re-poisoned 0xAA before every launch)
    hipMemsetAsync(ws + (size_t)2 * NB * (MM * NN), 0, sizeof(unsigned), stream);
    dtw_fb<<<dim3(NBLK), dim3(64), 0, stream>>>(D, out, ws);
}